// Round 1
// baseline (210.279 us; speedup 1.0000x reference)
//
#include <hip/hip_runtime.h>
#include <math.h>

// Problem constants (match reference)
#define B_    256
#define T_    4096
#define N_    8        // n
#define TWON_ 16       // 2n
#define H_    64
#define P_    144      // 2n + 2n^2
#define BLK   256
#define CHUNKS (T_ / BLK)          // 16
#define NBLK   (CHUNKS * B_)       // 4096 partial sums

// denominators
#define INV_MAIN  (1.0f / (float)(B_ * TWON_ * T_))   // 1/16777216 (data+physics share it)
#define INV_SUP   (1.0f / (float)(B_ * (P_ + TWON_))) // 1/40960

__device__ __forceinline__ float fast_tanh(float x) {
    // tanh(x) = 1 - 2/(e^{2x}+1). Clamp to keep e^{2x} finite.
    x = fminf(fmaxf(x, -15.0f), 15.0f);
    float e = __expf(2.0f * x);                  // v_mul + v_exp_f32
    float r = __builtin_amdgcn_rcpf(e + 1.0f);   // v_rcp_f32 (~1ulp)
    return fmaf(-2.0f, r, 1.0f);
}

__device__ __forceinline__ float wave_reduce(float v) {
    #pragma unroll
    for (int off = 32; off > 0; off >>= 1) v += __shfl_down(v, off, 64);
    return v;
}

// grid: (CHUNKS, B_), block: BLK threads. Each thread = one (b,t) point.
__global__ __launch_bounds__(BLK)
void pinn_main_kernel(const float* __restrict__ t_in,
                      const float* __restrict__ x_target,
                      const float* __restrict__ params_pred,
                      const float* __restrict__ W1,
                      const float* __restrict__ b1,
                      const float* __restrict__ W2,
                      const float* __restrict__ b2,
                      float* __restrict__ partials) {
    __shared__ float sW1[H_], sb1[H_], sW2[H_ * TWON_], sb2[TWON_];
    __shared__ float sg[N_], smu[N_], sPi[N_ * N_], sGam[N_ * N_];
    __shared__ float swsum[BLK / 64];

    const int tid = threadIdx.x;
    const int b   = blockIdx.y;

    // cooperative LDS staging
    for (int i = tid; i < H_ * TWON_; i += BLK) sW2[i] = W2[i];
    if (tid < H_)    { sW1[tid] = W1[tid]; sb1[tid] = b1[tid]; }
    if (tid < TWON_) { sb2[tid] = b2[tid]; }
    const float* pp = params_pred + b * P_;
    if (tid < N_) { sg[tid] = pp[tid]; smu[tid] = pp[N_ + tid]; }
    if (tid >= 64 && tid < 64 + N_ * N_)  sPi[tid - 64]   = pp[2 * N_ + (tid - 64)];
    if (tid >= 128 && tid < 128 + N_ * N_) sGam[tid - 128] = pp[2 * N_ + N_ * N_ + (tid - 128)];
    __syncthreads();

    const int tq = blockIdx.x * BLK + tid;
    const float tt = t_in[b * T_ + tq];

    // latent = tanh(t*W1+b1) @ W2 + b2 ; dlatent = ((1-h^2)*W1) @ W2
    float lat[TWON_], dlat[TWON_];
    #pragma unroll
    for (int k = 0; k < TWON_; ++k) { lat[k] = sb2[k]; dlat[k] = 0.0f; }

    for (int j = 0; j < H_; ++j) {
        const float w1 = sW1[j];
        const float pre = fmaf(tt, w1, sb1[j]);
        const float h  = fast_tanh(pre);
        const float dh = (1.0f - h * h) * w1;
        #pragma unroll
        for (int k = 0; k < TWON_; ++k) {
            const float w = sW2[j * TWON_ + k];
            lat[k]  = fmaf(h,  w, lat[k]);
            dlat[k] = fmaf(dh, w, dlat[k]);
        }
    }

    // observables: state = [a, relu(q-mu)], dstate = [da, (q-mu>0)?dq:0]
    float a[N_], xs[N_], da_[N_], dxs[N_];
    #pragma unroll
    for (int i = 0; i < N_; ++i) { a[i] = lat[i]; da_[i] = dlat[i]; }
    #pragma unroll
    for (int i = 0; i < N_; ++i) {
        const float qm = lat[N_ + i] - smu[i];
        xs[i]  = qm > 0.0f ? qm : 0.0f;
        dxs[i] = qm > 0.0f ? dlat[N_ + i] : 0.0f;
    }

    float acc = 0.0f;

    // data loss terms: (state[k] - x_target[b,k,t])^2, x_target stride T per k
    const float* xt = x_target + (size_t)b * TWON_ * T_ + tq;
    #pragma unroll
    for (int k = 0; k < N_; ++k) { const float d = a[k]  - xt[(size_t)k * T_];        acc = fmaf(d, d, acc); }
    #pragma unroll
    for (int k = 0; k < N_; ++k) { const float d = xs[k] - xt[(size_t)(N_ + k) * T_]; acc = fmaf(d, d, acc); }

    // physics: rhs_a = g + Pi@x - a ; rhs_x = (Gamma@a)*(mu - x)
    #pragma unroll
    for (int i = 0; i < N_; ++i) {
        float s1 = sg[i] - a[i];
        #pragma unroll
        for (int j = 0; j < N_; ++j) s1 = fmaf(sPi[i * N_ + j], xs[j], s1);
        float d = da_[i] - s1;
        acc = fmaf(d, d, acc);

        float s2 = 0.0f;
        #pragma unroll
        for (int j = 0; j < N_; ++j) s2 = fmaf(sGam[i * N_ + j], a[j], s2);
        s2 *= (smu[i] - xs[i]);
        d = dxs[i] - s2;
        acc = fmaf(d, d, acc);
    }

    // block reduce -> one partial per block
    float w = wave_reduce(acc);
    if ((tid & 63) == 0) swsum[tid >> 6] = w;
    __syncthreads();
    if (tid == 0) {
        float s = 0.0f;
        #pragma unroll
        for (int i = 0; i < BLK / 64; ++i) s += swsum[i];
        partials[blockIdx.y * gridDim.x + blockIdx.x] = s;
    }
}

// one block: reduce partials + supervised loss, write scalar
__global__ __launch_bounds__(BLK)
void pinn_finalize_kernel(const float* __restrict__ partials,
                          const float* __restrict__ params_pred,
                          const float* __restrict__ params_target,
                          const float* __restrict__ ic_pred,
                          const float* __restrict__ ic_target,
                          float* __restrict__ out) {
    __shared__ float swsum[BLK / 64];
    const int tid = threadIdx.x;

    float s_main = 0.0f;
    for (int i = tid; i < NBLK; i += BLK) s_main += partials[i];

    float s_sup = 0.0f;
    for (int i = tid; i < B_ * P_; i += BLK) {
        const float d = params_pred[i] - params_target[i];
        s_sup = fmaf(d, d, s_sup);
    }
    for (int i = tid; i < B_ * TWON_; i += BLK) {
        const float d = ic_pred[i] - ic_target[i];
        s_sup = fmaf(d, d, s_sup);
    }

    float v = s_main * INV_MAIN + s_sup * INV_SUP;
    float w = wave_reduce(v);
    if ((tid & 63) == 0) swsum[tid >> 6] = w;
    __syncthreads();
    if (tid == 0) {
        float s = 0.0f;
        #pragma unroll
        for (int i = 0; i < BLK / 64; ++i) s += swsum[i];
        out[0] = s;
    }
}

extern "C" void kernel_launch(void* const* d_in, const int* in_sizes, int n_in,
                              void* d_out, int out_size, void* d_ws, size_t ws_size,
                              hipStream_t stream) {
    const float* t_in          = (const float*)d_in[0];
    const float* x_target      = (const float*)d_in[1];
    const float* params_pred   = (const float*)d_in[2];
    const float* params_target = (const float*)d_in[3];
    const float* ic_pred       = (const float*)d_in[4];
    const float* ic_target     = (const float*)d_in[5];
    const float* W1            = (const float*)d_in[6];
    const float* b1            = (const float*)d_in[7];
    const float* W2            = (const float*)d_in[8];
    const float* b2            = (const float*)d_in[9];
    float* out = (float*)d_out;
    float* partials = (float*)d_ws;   // NBLK floats = 16 KB

    dim3 grid(CHUNKS, B_);
    pinn_main_kernel<<<grid, BLK, 0, stream>>>(t_in, x_target, params_pred,
                                               W1, b1, W2, b2, partials);
    pinn_finalize_kernel<<<1, BLK, 0, stream>>>(partials, params_pred, params_target,
                                                ic_pred, ic_target, out);
}

// Round 2
// 167.570 us; speedup vs baseline: 1.2549x; 1.2549x over previous
//
#include <hip/hip_runtime.h>
#include <math.h>

// Problem constants (match reference)
#define B_    256
#define T_    4096
#define N_    8        // n
#define TWON_ 16       // 2n
#define H_    64
#define P_    144      // 2n + 2n^2
#define BLK   256
#define CHUNKS (T_ / BLK)          // 16
#define NBLK   (CHUNKS * B_)       // 4096 partial sums
#define FBLK  1024                 // finalize block size

// denominators
#define INV_MAIN  (1.0f / (float)(B_ * TWON_ * T_))   // 1/16777216
#define INV_SUP   (1.0f / (float)(B_ * (P_ + TWON_))) // 1/40960

__device__ __forceinline__ float fast_tanh(float x) {
    // tanh(x) = 1 - 2/(e^{2x}+1). Clamp to keep e^{2x} finite.
    x = fminf(fmaxf(x, -15.0f), 15.0f);
    float e = __expf(2.0f * x);                  // v_mul + v_exp_f32
    float r = __builtin_amdgcn_rcpf(e + 1.0f);   // v_rcp_f32 (~1ulp)
    return fmaf(-2.0f, r, 1.0f);
}

__device__ __forceinline__ float wave_reduce(float v) {
    #pragma unroll
    for (int off = 32; off > 0; off >>= 1) v += __shfl_down(v, off, 64);
    return v;
}

// grid: (CHUNKS, B_), block: BLK threads. Each thread = one (b,t) point.
// Blocks with blockIdx.x==0 additionally fold in batch b's supervised loss.
__global__ __launch_bounds__(BLK)
void pinn_main_kernel(const float* __restrict__ t_in,
                      const float* __restrict__ x_target,
                      const float* __restrict__ params_pred,
                      const float* __restrict__ params_target,
                      const float* __restrict__ ic_pred,
                      const float* __restrict__ ic_target,
                      const float* __restrict__ W1,
                      const float* __restrict__ b1,
                      const float* __restrict__ W2,
                      const float* __restrict__ b2,
                      float* __restrict__ partials) {
    __shared__ float sW1[H_], sb1[H_], sW2[H_ * TWON_], sb2[TWON_];
    __shared__ float sg[N_], smu[N_], sPi[N_ * N_], sGam[N_ * N_];
    __shared__ float swsum[BLK / 64];

    const int tid = threadIdx.x;
    const int b   = blockIdx.y;

    // cooperative LDS staging
    for (int i = tid; i < H_ * TWON_; i += BLK) sW2[i] = W2[i];
    if (tid < H_)    { sW1[tid] = W1[tid]; sb1[tid] = b1[tid]; }
    if (tid < TWON_) { sb2[tid] = b2[tid]; }
    const float* pp = params_pred + b * P_;
    if (tid < N_) { sg[tid] = pp[tid]; smu[tid] = pp[N_ + tid]; }
    if (tid >= 64 && tid < 64 + N_ * N_)   sPi[tid - 64]   = pp[2 * N_ + (tid - 64)];
    if (tid >= 128 && tid < 128 + N_ * N_) sGam[tid - 128] = pp[2 * N_ + N_ * N_ + (tid - 128)];

    // supervised loss (only x==0 blocks; one per batch) — runs before barrier,
    // independent of LDS contents.
    float sup = 0.0f;
    if (blockIdx.x == 0) {
        if (tid < P_) {
            const float d = pp[tid] - params_target[b * P_ + tid];
            sup = d * d;
        }
        if (tid < TWON_) {
            const float d = ic_pred[b * TWON_ + tid] - ic_target[b * TWON_ + tid];
            sup = fmaf(d, d, sup);
        }
    }
    __syncthreads();

    const int tq = blockIdx.x * BLK + tid;
    const float tt = t_in[b * T_ + tq];

    // latent = tanh(t*W1+b1) @ W2 + b2 ; dlatent = ((1-h^2)*W1) @ W2
    float lat[TWON_], dlat[TWON_];
    #pragma unroll
    for (int k = 0; k < TWON_; ++k) { lat[k] = sb2[k]; dlat[k] = 0.0f; }

    for (int j = 0; j < H_; ++j) {
        const float w1 = sW1[j];
        const float pre = fmaf(tt, w1, sb1[j]);
        const float h  = fast_tanh(pre);
        const float dh = (1.0f - h * h) * w1;
        #pragma unroll
        for (int k = 0; k < TWON_; ++k) {
            const float w = sW2[j * TWON_ + k];
            lat[k]  = fmaf(h,  w, lat[k]);
            dlat[k] = fmaf(dh, w, dlat[k]);
        }
    }

    // observables: state = [a, relu(q-mu)], dstate = [da, (q-mu>0)?dq:0]
    float a[N_], xs[N_], da_[N_], dxs[N_];
    #pragma unroll
    for (int i = 0; i < N_; ++i) { a[i] = lat[i]; da_[i] = dlat[i]; }
    #pragma unroll
    for (int i = 0; i < N_; ++i) {
        const float qm = lat[N_ + i] - smu[i];
        xs[i]  = qm > 0.0f ? qm : 0.0f;
        dxs[i] = qm > 0.0f ? dlat[N_ + i] : 0.0f;
    }

    float acc = 0.0f;

    // data loss terms: (state[k] - x_target[b,k,t])^2, x_target stride T per k
    const float* xt = x_target + (size_t)b * TWON_ * T_ + tq;
    #pragma unroll
    for (int k = 0; k < N_; ++k) { const float d = a[k]  - xt[(size_t)k * T_];        acc = fmaf(d, d, acc); }
    #pragma unroll
    for (int k = 0; k < N_; ++k) { const float d = xs[k] - xt[(size_t)(N_ + k) * T_]; acc = fmaf(d, d, acc); }

    // physics: rhs_a = g + Pi@x - a ; rhs_x = (Gamma@a)*(mu - x)
    #pragma unroll
    for (int i = 0; i < N_; ++i) {
        float s1 = sg[i] - a[i];
        #pragma unroll
        for (int j = 0; j < N_; ++j) s1 = fmaf(sPi[i * N_ + j], xs[j], s1);
        float d = da_[i] - s1;
        acc = fmaf(d, d, acc);

        float s2 = 0.0f;
        #pragma unroll
        for (int j = 0; j < N_; ++j) s2 = fmaf(sGam[i * N_ + j], a[j], s2);
        s2 *= (smu[i] - xs[i]);
        d = dxs[i] - s2;
        acc = fmaf(d, d, acc);
    }

    // fully-scaled per-thread contribution, then block reduce
    float v = fmaf(acc, INV_MAIN, sup * INV_SUP);
    float w = wave_reduce(v);
    if ((tid & 63) == 0) swsum[tid >> 6] = w;
    __syncthreads();
    if (tid == 0) {
        float s = 0.0f;
        #pragma unroll
        for (int i = 0; i < BLK / 64; ++i) s += swsum[i];
        partials[blockIdx.y * gridDim.x + blockIdx.x] = s;
    }
}

// one block of 1024: reduce NBLK pre-scaled partials -> scalar
__global__ __launch_bounds__(FBLK)
void pinn_finalize_kernel(const float* __restrict__ partials,
                          float* __restrict__ out) {
    __shared__ float swsum[FBLK / 64];
    const int tid = threadIdx.x;

    const float4* p4 = (const float4*)partials;   // NBLK/4 = 1024 float4s
    const float4 v4 = p4[tid];
    float v = (v4.x + v4.y) + (v4.z + v4.w);

    float w = wave_reduce(v);
    if ((tid & 63) == 0) swsum[tid >> 6] = w;
    __syncthreads();
    if (tid == 0) {
        float s = 0.0f;
        #pragma unroll
        for (int i = 0; i < FBLK / 64; ++i) s += swsum[i];
        out[0] = s;
    }
}

extern "C" void kernel_launch(void* const* d_in, const int* in_sizes, int n_in,
                              void* d_out, int out_size, void* d_ws, size_t ws_size,
                              hipStream_t stream) {
    const float* t_in          = (const float*)d_in[0];
    const float* x_target      = (const float*)d_in[1];
    const float* params_pred   = (const float*)d_in[2];
    const float* params_target = (const float*)d_in[3];
    const float* ic_pred       = (const float*)d_in[4];
    const float* ic_target     = (const float*)d_in[5];
    const float* W1            = (const float*)d_in[6];
    const float* b1            = (const float*)d_in[7];
    const float* W2            = (const float*)d_in[8];
    const float* b2            = (const float*)d_in[9];
    float* out = (float*)d_out;
    float* partials = (float*)d_ws;   // NBLK floats = 16 KB

    dim3 grid(CHUNKS, B_);
    pinn_main_kernel<<<grid, BLK, 0, stream>>>(t_in, x_target, params_pred,
                                               params_target, ic_pred, ic_target,
                                               W1, b1, W2, b2, partials);
    pinn_finalize_kernel<<<1, FBLK, 0, stream>>>(partials, out);
}

// Round 4
// 158.326 us; speedup vs baseline: 1.3281x; 1.0584x over previous
//
#include <hip/hip_runtime.h>
#include <math.h>

// Problem constants (match reference)
#define B_    256
#define T_    4096
#define N_    8        // n
#define TWON_ 16       // 2n
#define H_    64
#define P_    144      // 2n + 2n^2
#define BLK   256
#define CHUNKS (T_ / BLK)          // 16 blocks along T, each block = 256 points
#define LSTRIDE 20                 // LDS row stride (floats): 2-way banks on write (free), 16B-aligned rows

// denominators
#define INV_MAIN  (1.0f / (float)(B_ * TWON_ * T_))   // 1/16777216
#define INV_SUP   (1.0f / (float)(B_ * (P_ + TWON_))) // 1/40960

typedef __fp16   half2_t __attribute__((ext_vector_type(2)));  // cvt_pkrtz result type
typedef _Float16 half8_t __attribute__((ext_vector_type(8)));  // MFMA operand type
typedef float    f32x4   __attribute__((ext_vector_type(4)));

union HPack { half2_t h2[4]; half8_t h8; };  // union pun: same 16 bytes

__device__ __forceinline__ float wave_reduce(float v) {
    #pragma unroll
    for (int off = 32; off > 0; off >>= 1) v += __shfl_down(v, off, 64);
    return v;
}

// grid: (CHUNKS, B_), block 256 = 4 waves. Each wave: 64 points via 4 MFMA tiles
// of 16 points. MLP matvecs on matrix cores (f16 in, f32 acc); tanh on VALU.
__global__ __launch_bounds__(BLK)
void pinn_main_kernel(const float* __restrict__ t_in,
                      const float* __restrict__ x_target,
                      const float* __restrict__ params_pred,
                      const float* __restrict__ params_target,
                      const float* __restrict__ ic_pred,
                      const float* __restrict__ ic_target,
                      const float* __restrict__ W1,
                      const float* __restrict__ b1,
                      const float* __restrict__ W2,
                      const float* __restrict__ b2,
                      float* __restrict__ out) {
    __shared__ float slat [BLK * LSTRIDE];   // 20 KB: lat rows (includes +b2)
    __shared__ float sdlat[BLK * LSTRIDE];   // 20 KB: dlat rows
    __shared__ float sg[N_], smu[N_], sPi[N_ * N_], sGam[N_ * N_];
    __shared__ float swsum[BLK / 64];

    const int tid  = threadIdx.x;
    const int b    = blockIdx.y;
    const int lane = tid & 63;
    const int wv   = tid >> 6;
    const int q    = lane >> 4;      // quad
    const int mn   = lane & 15;      // A-row (point-in-tile) == B/C col n
    const int k0   = q * 8;          // this lane's k-group base (within K=32 half)

    // ---- params staging for epilogue ----
    const float* pp = params_pred + b * P_;
    if (tid < N_) { sg[tid] = pp[tid]; smu[tid] = pp[N_ + tid]; }
    if (tid >= 64  && tid < 64 + N_ * N_)  sPi[tid - 64]   = pp[2 * N_ + (tid - 64)];
    if (tid >= 128 && tid < 128 + N_ * N_) sGam[tid - 128] = pp[2 * N_ + N_ * N_ + (tid - 128)];

    // ---- supervised loss (one block column per batch) ----
    float sup = 0.0f;
    if (blockIdx.x == 0) {
        if (tid < P_) {
            const float d = pp[tid] - params_target[b * P_ + tid];
            sup = d * d;
        }
        if (tid < TWON_) {
            const float d = ic_pred[b * TWON_ + tid] - ic_target[b * TWON_ + tid];
            sup = fmaf(d, d, sup);
        }
    }

    // ---- per-lane weight setup (once) ----
    // zw = 2*W1[k], zb = 2*b1[k]  (tanh(x) = 1 - 2/(e^{2x}+1))
    float zwlo[8], zblo[8], zwhi[8], zbhi[8];
    HPack Blo, Bhi, Plo, Phi;   // B[k][n]=W2[k][n]; B'[k][n]=W1[k]*W2[k][n]
    #pragma unroll
    for (int j2 = 0; j2 < 4; ++j2) {
        const int ka = k0 + 2 * j2, kb = ka + 1;
        const float w1a = W1[ka],      w1b = W1[kb];
        const float w1c = W1[32 + ka], w1d = W1[32 + kb];
        zwlo[2*j2] = 2.0f * w1a; zwlo[2*j2+1] = 2.0f * w1b;
        zwhi[2*j2] = 2.0f * w1c; zwhi[2*j2+1] = 2.0f * w1d;
        zblo[2*j2] = 2.0f * b1[ka];      zblo[2*j2+1] = 2.0f * b1[kb];
        zbhi[2*j2] = 2.0f * b1[32 + ka]; zbhi[2*j2+1] = 2.0f * b1[32 + kb];
        const float wa = W2[ka * TWON_ + mn],        wb = W2[kb * TWON_ + mn];
        const float wc = W2[(32 + ka) * TWON_ + mn], wd = W2[(32 + kb) * TWON_ + mn];
        Blo.h2[j2] = __builtin_amdgcn_cvt_pkrtz(wa, wb);
        Bhi.h2[j2] = __builtin_amdgcn_cvt_pkrtz(wc, wd);
        Plo.h2[j2] = __builtin_amdgcn_cvt_pkrtz(w1a * wa, w1b * wb);
        Phi.h2[j2] = __builtin_amdgcn_cvt_pkrtz(w1c * wc, w1d * wd);
    }
    const float b2n = b2[mn];

    // t for this wave's 64 points (local points wv*64 + lane)
    const float treg = t_in[b * T_ + blockIdx.x * BLK + wv * 64 + lane];

    // ---- 4 tiles of 16 points each ----
    #pragma unroll
    for (int ti = 0; ti < 4; ++ti) {
        const float tt = __shfl(treg, ti * 16 + mn, 64);

        HPack Ah_lo, Ag_lo, Ah_hi, Ag_hi;
        #pragma unroll
        for (int j2 = 0; j2 < 4; ++j2) {
            // low half (k = k0+2j2, k0+2j2+1)
            float z0 = fmaf(tt, zwlo[2*j2],   zblo[2*j2]);
            float z1 = fmaf(tt, zwlo[2*j2+1], zblo[2*j2+1]);
            float r0 = __builtin_amdgcn_rcpf(__expf(z0) + 1.0f);
            float r1 = __builtin_amdgcn_rcpf(__expf(z1) + 1.0f);
            float h0 = fmaf(-2.0f, r0, 1.0f), h1 = fmaf(-2.0f, r1, 1.0f);
            float g0 = fmaf(-h0, h0, 1.0f),   g1 = fmaf(-h1, h1, 1.0f);
            Ah_lo.h2[j2] = __builtin_amdgcn_cvt_pkrtz(h0, h1);
            Ag_lo.h2[j2] = __builtin_amdgcn_cvt_pkrtz(g0, g1);
            // high half (k+32)
            z0 = fmaf(tt, zwhi[2*j2],   zbhi[2*j2]);
            z1 = fmaf(tt, zwhi[2*j2+1], zbhi[2*j2+1]);
            r0 = __builtin_amdgcn_rcpf(__expf(z0) + 1.0f);
            r1 = __builtin_amdgcn_rcpf(__expf(z1) + 1.0f);
            h0 = fmaf(-2.0f, r0, 1.0f); h1 = fmaf(-2.0f, r1, 1.0f);
            g0 = fmaf(-h0, h0, 1.0f);   g1 = fmaf(-h1, h1, 1.0f);
            Ah_hi.h2[j2] = __builtin_amdgcn_cvt_pkrtz(h0, h1);
            Ag_hi.h2[j2] = __builtin_amdgcn_cvt_pkrtz(g0, g1);
        }

        f32x4 lat = {b2n, b2n, b2n, b2n};
        lat = __builtin_amdgcn_mfma_f32_16x16x32_f16(Ah_lo.h8, Blo.h8, lat, 0, 0, 0);
        lat = __builtin_amdgcn_mfma_f32_16x16x32_f16(Ah_hi.h8, Bhi.h8, lat, 0, 0, 0);
        f32x4 dl = {0.0f, 0.0f, 0.0f, 0.0f};
        dl = __builtin_amdgcn_mfma_f32_16x16x32_f16(Ag_lo.h8, Plo.h8, dl, 0, 0, 0);
        dl = __builtin_amdgcn_mfma_f32_16x16x32_f16(Ag_hi.h8, Phi.h8, dl, 0, 0, 0);

        // C/D: col = lane&15 (=n), row = quad*4 + reg (= point-in-tile)
        const int rowbase = wv * 64 + ti * 16 + 4 * q;
        #pragma unroll
        for (int r = 0; r < 4; ++r) {
            slat [(rowbase + r) * LSTRIDE + mn] = lat[r];
            sdlat[(rowbase + r) * LSTRIDE + mn] = dl[r];
        }
    }
    __syncthreads();

    // ---- epilogue: one thread per point, verified round-2 code ----
    float lat[TWON_], dlat[TWON_];
    {
        const float4* lr = (const float4*)&slat [tid * LSTRIDE];
        const float4* dr = (const float4*)&sdlat[tid * LSTRIDE];
        #pragma unroll
        for (int i = 0; i < 4; ++i) { ((float4*)lat)[i] = lr[i]; ((float4*)dlat)[i] = dr[i]; }
    }

    float a[N_], xs[N_], da_[N_], dxs[N_];
    #pragma unroll
    for (int i = 0; i < N_; ++i) { a[i] = lat[i]; da_[i] = dlat[i]; }
    #pragma unroll
    for (int i = 0; i < N_; ++i) {
        const float qm = lat[N_ + i] - smu[i];
        xs[i]  = qm > 0.0f ? qm : 0.0f;
        dxs[i] = qm > 0.0f ? dlat[N_ + i] : 0.0f;
    }

    float acc = 0.0f;
    const int tq = blockIdx.x * BLK + tid;
    const float* xt = x_target + (size_t)b * TWON_ * T_ + tq;
    #pragma unroll
    for (int k = 0; k < N_; ++k) { const float d = a[k]  - xt[(size_t)k * T_];        acc = fmaf(d, d, acc); }
    #pragma unroll
    for (int k = 0; k < N_; ++k) { const float d = xs[k] - xt[(size_t)(N_ + k) * T_]; acc = fmaf(d, d, acc); }

    #pragma unroll
    for (int i = 0; i < N_; ++i) {
        float s1 = sg[i] - a[i];
        #pragma unroll
        for (int j = 0; j < N_; ++j) s1 = fmaf(sPi[i * N_ + j], xs[j], s1);
        float d = da_[i] - s1;
        acc = fmaf(d, d, acc);

        float s2 = 0.0f;
        #pragma unroll
        for (int j = 0; j < N_; ++j) s2 = fmaf(sGam[i * N_ + j], a[j], s2);
        s2 *= (smu[i] - xs[i]);
        d = dxs[i] - s2;
        acc = fmaf(d, d, acc);
    }

    // scale, reduce, one atomic per block
    float v = fmaf(acc, INV_MAIN, sup * INV_SUP);
    float w = wave_reduce(v);
    if ((tid & 63) == 0) swsum[tid >> 6] = w;
    __syncthreads();
    if (tid == 0) {
        float s = 0.0f;
        #pragma unroll
        for (int i = 0; i < BLK / 64; ++i) s += swsum[i];
        atomicAdd(out, s);
    }
}

extern "C" void kernel_launch(void* const* d_in, const int* in_sizes, int n_in,
                              void* d_out, int out_size, void* d_ws, size_t ws_size,
                              hipStream_t stream) {
    const float* t_in          = (const float*)d_in[0];
    const float* x_target      = (const float*)d_in[1];
    const float* params_pred   = (const float*)d_in[2];
    const float* params_target = (const float*)d_in[3];
    const float* ic_pred       = (const float*)d_in[4];
    const float* ic_target     = (const float*)d_in[5];
    const float* W1            = (const float*)d_in[6];
    const float* b1            = (const float*)d_in[7];
    const float* W2            = (const float*)d_in[8];
    const float* b2            = (const float*)d_in[9];
    float* out = (float*)d_out;

    (void)hipMemsetAsync(out, 0, sizeof(float), stream);
    dim3 grid(CHUNKS, B_);
    pinn_main_kernel<<<grid, BLK, 0, stream>>>(t_in, x_target, params_pred,
                                               params_target, ic_pred, ic_target,
                                               W1, b1, W2, b2, out);
}

// Round 5
// 157.789 us; speedup vs baseline: 1.3327x; 1.0034x over previous
//
#include <hip/hip_runtime.h>
#include <math.h>

// Problem constants (match reference)
#define B_    256
#define T_    4096
#define N_    8        // n
#define TWON_ 16       // 2n
#define H_    64
#define P_    144      // 2n + 2n^2
#define BLK   256
#define CHUNKS (T_ / BLK)   // 16 blocks along T, each block = 256 points
#define PSTRIDE 20          // LDS row stride in half2 units: 80 B rows, 16B-aligned, 2-way banks

// denominators
#define INV_MAIN  (1.0f / (float)(B_ * TWON_ * T_))   // 1/16777216
#define INV_SUP   (1.0f / (float)(B_ * (P_ + TWON_))) // 1/40960

#define TWO_LOG2E 2.8853900817779268f   // 2*log2(e): e^{2x} = 2^{x*TWO_LOG2E}

typedef __fp16   half2_t __attribute__((ext_vector_type(2)));  // cvt_pkrtz result type
typedef _Float16 half8_t __attribute__((ext_vector_type(8)));  // MFMA operand type
typedef float    f32x4   __attribute__((ext_vector_type(4)));

union HPack { half2_t h2[4]; half8_t h8; };   // MFMA operand pun
union RPack { uint4 u4[4]; half2_t h2[16]; }; // LDS row read pun (64 B)

__device__ __forceinline__ float wave_reduce(float v) {
    #pragma unroll
    for (int off = 32; off > 0; off >>= 1) v += __shfl_down(v, off, 64);
    return v;
}

// grid: (CHUNKS, B_), block 256 = 4 waves. Each wave: 64 points via 4 MFMA tiles
// of 16 points. MLP matvecs on matrix cores (f16 in, f32 acc); tanh on VALU.
// lat/dlat round-trip LDS as packed half2 (20.5 KB -> 7 blocks/CU occupancy).
__global__ __launch_bounds__(BLK)
void pinn_main_kernel(const float* __restrict__ t_in,
                      const float* __restrict__ x_target,
                      const float* __restrict__ params_pred,
                      const float* __restrict__ params_target,
                      const float* __restrict__ ic_pred,
                      const float* __restrict__ ic_target,
                      const float* __restrict__ W1,
                      const float* __restrict__ b1,
                      const float* __restrict__ W2,
                      const float* __restrict__ b2,
                      float* __restrict__ out) {
    __shared__ __align__(16) half2_t spk[BLK * PSTRIDE];  // 20.5 KB: (lat, dlat) packed
    __shared__ float sg[N_], smu[N_], sPi[N_ * N_], sGam[N_ * N_];
    __shared__ float swsum[BLK / 64];

    const int tid  = threadIdx.x;
    const int b    = blockIdx.y;
    const int lane = tid & 63;
    const int wv   = tid >> 6;
    const int q    = lane >> 4;      // quad
    const int mn   = lane & 15;      // A-row (point-in-tile) == B/C col n
    const int k0   = q * 8;          // this lane's k-group base (within K=32 half)

    // ---- params staging for epilogue ----
    const float* pp = params_pred + b * P_;
    if (tid < N_) { sg[tid] = pp[tid]; smu[tid] = pp[N_ + tid]; }
    if (tid >= 64  && tid < 64 + N_ * N_)  sPi[tid - 64]   = pp[2 * N_ + (tid - 64)];
    if (tid >= 128 && tid < 128 + N_ * N_) sGam[tid - 128] = pp[2 * N_ + N_ * N_ + (tid - 128)];

    // ---- supervised loss (one block column per batch) ----
    float sup = 0.0f;
    if (blockIdx.x == 0) {
        if (tid < P_) {
            const float d = pp[tid] - params_target[b * P_ + tid];
            sup = d * d;
        }
        if (tid < TWON_) {
            const float d = ic_pred[b * TWON_ + tid] - ic_target[b * TWON_ + tid];
            sup = fmaf(d, d, sup);
        }
    }

    // ---- per-lane weight setup (once) ----
    // E = e^{2x} = exp2(x*2log2e); tanh = 1 - 2/(E+1). exp2(+-inf) limits give h=+-1, g=0.
    float zwlo[8], zblo[8], zwhi[8], zbhi[8];
    HPack Blo, Bhi, Plo, Phi;   // B[k][n]=W2[k][n]; B'[k][n]=W1[k]*W2[k][n]
    #pragma unroll
    for (int j2 = 0; j2 < 4; ++j2) {
        const int ka = k0 + 2 * j2, kb = ka + 1;
        const float w1a = W1[ka],      w1b = W1[kb];
        const float w1c = W1[32 + ka], w1d = W1[32 + kb];
        zwlo[2*j2] = TWO_LOG2E * w1a; zwlo[2*j2+1] = TWO_LOG2E * w1b;
        zwhi[2*j2] = TWO_LOG2E * w1c; zwhi[2*j2+1] = TWO_LOG2E * w1d;
        zblo[2*j2] = TWO_LOG2E * b1[ka];      zblo[2*j2+1] = TWO_LOG2E * b1[kb];
        zbhi[2*j2] = TWO_LOG2E * b1[32 + ka]; zbhi[2*j2+1] = TWO_LOG2E * b1[32 + kb];
        const float wa = W2[ka * TWON_ + mn],        wb = W2[kb * TWON_ + mn];
        const float wc = W2[(32 + ka) * TWON_ + mn], wd = W2[(32 + kb) * TWON_ + mn];
        Blo.h2[j2] = __builtin_amdgcn_cvt_pkrtz(wa, wb);
        Bhi.h2[j2] = __builtin_amdgcn_cvt_pkrtz(wc, wd);
        Plo.h2[j2] = __builtin_amdgcn_cvt_pkrtz(w1a * wa, w1b * wb);
        Phi.h2[j2] = __builtin_amdgcn_cvt_pkrtz(w1c * wc, w1d * wd);
    }
    const float b2n = b2[mn];

    // t for this wave's 64 points (local points wv*64 + lane)
    const float treg = t_in[b * T_ + blockIdx.x * BLK + wv * 64 + lane];

    // ---- 4 tiles of 16 points each ----
    #pragma unroll
    for (int ti = 0; ti < 4; ++ti) {
        const float tt = __shfl(treg, ti * 16 + mn, 64);

        HPack Ah_lo, Ag_lo, Ah_hi, Ag_hi;
        #pragma unroll
        for (int j2 = 0; j2 < 4; ++j2) {
            // low half (k = k0+2j2, k0+2j2+1)
            float e0 = __builtin_amdgcn_exp2f(fmaf(tt, zwlo[2*j2],   zblo[2*j2]));
            float e1 = __builtin_amdgcn_exp2f(fmaf(tt, zwlo[2*j2+1], zblo[2*j2+1]));
            float r0 = __builtin_amdgcn_rcpf(e0 + 1.0f);
            float r1 = __builtin_amdgcn_rcpf(e1 + 1.0f);
            float h0 = fmaf(-2.0f, r0, 1.0f), h1 = fmaf(-2.0f, r1, 1.0f);
            float g0 = fmaf(-h0, h0, 1.0f),   g1 = fmaf(-h1, h1, 1.0f);
            Ah_lo.h2[j2] = __builtin_amdgcn_cvt_pkrtz(h0, h1);
            Ag_lo.h2[j2] = __builtin_amdgcn_cvt_pkrtz(g0, g1);
            // high half (k+32)
            e0 = __builtin_amdgcn_exp2f(fmaf(tt, zwhi[2*j2],   zbhi[2*j2]));
            e1 = __builtin_amdgcn_exp2f(fmaf(tt, zwhi[2*j2+1], zbhi[2*j2+1]));
            r0 = __builtin_amdgcn_rcpf(e0 + 1.0f);
            r1 = __builtin_amdgcn_rcpf(e1 + 1.0f);
            h0 = fmaf(-2.0f, r0, 1.0f); h1 = fmaf(-2.0f, r1, 1.0f);
            g0 = fmaf(-h0, h0, 1.0f);   g1 = fmaf(-h1, h1, 1.0f);
            Ah_hi.h2[j2] = __builtin_amdgcn_cvt_pkrtz(h0, h1);
            Ag_hi.h2[j2] = __builtin_amdgcn_cvt_pkrtz(g0, g1);
        }

        f32x4 lat = {b2n, b2n, b2n, b2n};
        lat = __builtin_amdgcn_mfma_f32_16x16x32_f16(Ah_lo.h8, Blo.h8, lat, 0, 0, 0);
        lat = __builtin_amdgcn_mfma_f32_16x16x32_f16(Ah_hi.h8, Bhi.h8, lat, 0, 0, 0);
        f32x4 dl = {0.0f, 0.0f, 0.0f, 0.0f};
        dl = __builtin_amdgcn_mfma_f32_16x16x32_f16(Ag_lo.h8, Plo.h8, dl, 0, 0, 0);
        dl = __builtin_amdgcn_mfma_f32_16x16x32_f16(Ag_hi.h8, Phi.h8, dl, 0, 0, 0);

        // C/D: col = lane&15 (=n), row = quad*4 + reg (= point-in-tile)
        // pack (lat, dlat) into one half2 per component
        const int rowbase = wv * 64 + ti * 16 + 4 * q;
        #pragma unroll
        for (int r = 0; r < 4; ++r) {
            spk[(rowbase + r) * PSTRIDE + mn] = __builtin_amdgcn_cvt_pkrtz(lat[r], dl[r]);
        }
    }
    __syncthreads();

    // ---- epilogue: one thread per point ----
    float lat[TWON_], dlat[TWON_];
    {
        RPack rp;
        const uint4* pr = (const uint4*)&spk[tid * PSTRIDE];  // 80-B rows: 16B aligned
        #pragma unroll
        for (int c = 0; c < 4; ++c) rp.u4[c] = pr[c];
        #pragma unroll
        for (int i = 0; i < TWON_; ++i) { lat[i] = (float)rp.h2[i].x; dlat[i] = (float)rp.h2[i].y; }
    }

    float a[N_], xs[N_], da_[N_], dxs[N_];
    #pragma unroll
    for (int i = 0; i < N_; ++i) { a[i] = lat[i]; da_[i] = dlat[i]; }
    #pragma unroll
    for (int i = 0; i < N_; ++i) {
        const float qm = lat[N_ + i] - smu[i];
        xs[i]  = qm > 0.0f ? qm : 0.0f;
        dxs[i] = qm > 0.0f ? dlat[N_ + i] : 0.0f;
    }

    float acc = 0.0f;
    const int tq = blockIdx.x * BLK + tid;
    const float* xt = x_target + (size_t)b * TWON_ * T_ + tq;
    #pragma unroll
    for (int k = 0; k < N_; ++k) { const float d = a[k]  - xt[(size_t)k * T_];        acc = fmaf(d, d, acc); }
    #pragma unroll
    for (int k = 0; k < N_; ++k) { const float d = xs[k] - xt[(size_t)(N_ + k) * T_]; acc = fmaf(d, d, acc); }

    #pragma unroll
    for (int i = 0; i < N_; ++i) {
        float s1 = sg[i] - a[i];
        #pragma unroll
        for (int j = 0; j < N_; ++j) s1 = fmaf(sPi[i * N_ + j], xs[j], s1);
        float d = da_[i] - s1;
        acc = fmaf(d, d, acc);

        float s2 = 0.0f;
        #pragma unroll
        for (int j = 0; j < N_; ++j) s2 = fmaf(sGam[i * N_ + j], a[j], s2);
        s2 *= (smu[i] - xs[i]);
        d = dxs[i] - s2;
        acc = fmaf(d, d, acc);
    }

    // scale, reduce, one atomic per block
    float v = fmaf(acc, INV_MAIN, sup * INV_SUP);
    float w = wave_reduce(v);
    if ((tid & 63) == 0) swsum[tid >> 6] = w;
    __syncthreads();
    if (tid == 0) {
        float s = 0.0f;
        #pragma unroll
        for (int i = 0; i < BLK / 64; ++i) s += swsum[i];
        atomicAdd(out, s);
    }
}

extern "C" void kernel_launch(void* const* d_in, const int* in_sizes, int n_in,
                              void* d_out, int out_size, void* d_ws, size_t ws_size,
                              hipStream_t stream) {
    const float* t_in          = (const float*)d_in[0];
    const float* x_target      = (const float*)d_in[1];
    const float* params_pred   = (const float*)d_in[2];
    const float* params_target = (const float*)d_in[3];
    const float* ic_pred       = (const float*)d_in[4];
    const float* ic_target     = (const float*)d_in[5];
    const float* W1            = (const float*)d_in[6];
    const float* b1            = (const float*)d_in[7];
    const float* W2            = (const float*)d_in[8];
    const float* b2            = (const float*)d_in[9];
    float* out = (float*)d_out;

    (void)hipMemsetAsync(out, 0, sizeof(float), stream);
    dim3 grid(CHUNKS, B_);
    pinn_main_kernel<<<grid, BLK, 0, stream>>>(t_in, x_target, params_pred,
                                               params_target, ic_pred, ic_target,
                                               W1, b1, W2, b2, out);
}

// Round 6
// 130.787 us; speedup vs baseline: 1.6078x; 1.2065x over previous
//
#include <hip/hip_runtime.h>
#include <math.h>

// Problem constants (match reference)
#define B_    256
#define T_    4096
#define N_    8        // n
#define TWON_ 16       // 2n
#define H_    64
#define P_    144      // 2n + 2n^2
#define WBLK  64                 // one wave per block
#define NBLKX (T_ / WBLK)        // 64 blocks along T
#define NPART (NBLKX * B_)       // 16384 partials
#define PSTRIDE 20               // LDS row stride in half2 units: 80 B rows, 16B-aligned
#define FBLK  1024               // finalize block size

// denominators
#define INV_MAIN  (1.0f / (float)(B_ * TWON_ * T_))   // 1/16777216
#define INV_SUP   (1.0f / (float)(B_ * (P_ + TWON_))) // 1/40960

#define TWO_LOG2E 2.8853900817779268f   // 2*log2(e): e^{2x} = 2^{x*TWO_LOG2E}

typedef __fp16   half2_t __attribute__((ext_vector_type(2)));  // cvt_pkrtz result type
typedef _Float16 half8_t __attribute__((ext_vector_type(8)));  // MFMA operand type
typedef float    f32x4   __attribute__((ext_vector_type(4)));

union HPack { half2_t h2[4]; half8_t h8; };   // MFMA operand pun
union RPack { uint4 u4[4]; half2_t h2[16]; }; // LDS row read pun (64 B)

__device__ __forceinline__ float wave_reduce(float v) {
    #pragma unroll
    for (int off = 32; off > 0; off >>= 1) v += __shfl_down(v, off, 64);
    return v;
}

// grid: (NBLKX, B_), block = 64 (one wave). Wave computes its 64 points via
// 4 MFMA tiles of 16 points; lat/dlat round-trip LDS packed half2 (5.1 KB).
// No inter-wave coupling; x_target prefetched at entry; params via scalar loads.
__global__ __launch_bounds__(WBLK, 5)
void pinn_main_kernel(const float* __restrict__ t_in,
                      const float* __restrict__ x_target,
                      const float* __restrict__ params_pred,
                      const float* __restrict__ params_target,
                      const float* __restrict__ ic_pred,
                      const float* __restrict__ ic_target,
                      const float* __restrict__ W1,
                      const float* __restrict__ b1,
                      const float* __restrict__ W2,
                      const float* __restrict__ b2,
                      float* __restrict__ partials) {
    __shared__ __align__(16) half2_t spk[WBLK * PSTRIDE];  // 5.1 KB: (lat, dlat) packed

    const int lane = threadIdx.x;    // 0..63
    const int b    = blockIdx.y;
    const int q    = lane >> 4;      // quad
    const int mn   = lane & 15;      // A-row (point-in-tile) == B/C col n
    const int k0   = q * 8;          // this lane's k-group base (within K=32 half)

    const float* pp = params_pred + b * P_;   // uniform -> scalar loads

    // ---- prefetch x_target for this thread's point (16 loads in flight) ----
    const int tq = blockIdx.x * WBLK + lane;
    const float* xt = x_target + (size_t)b * TWON_ * T_ + tq;
    float xtv[TWON_];
    #pragma unroll
    for (int k = 0; k < TWON_; ++k) xtv[k] = xt[(size_t)k * T_];

    // ---- supervised loss (blocks with x==0; one per batch) ----
    float sup = 0.0f;
    if (blockIdx.x == 0) {
        #pragma unroll
        for (int i = lane; i < P_; i += WBLK) {   // 144 elems: lanes 0..15 take 3 iters
            const float d = pp[i] - params_target[b * P_ + i];
            sup = fmaf(d, d, sup);
        }
        if (lane < TWON_) {
            const float d = ic_pred[b * TWON_ + lane] - ic_target[b * TWON_ + lane];
            sup = fmaf(d, d, sup);
        }
    }

    // ---- per-lane weight setup ----
    // E = e^{2x} = exp2(x*2log2e); tanh = 1 - 2/(E+1). exp2 limits give h=+-1, g=0.
    float zwlo[8], zblo[8], zwhi[8], zbhi[8];
    HPack Blo, Bhi, Plo, Phi;   // B[k][n]=W2[k][n]; B'[k][n]=W1[k]*W2[k][n]
    #pragma unroll
    for (int j2 = 0; j2 < 4; ++j2) {
        const int ka = k0 + 2 * j2, kb = ka + 1;
        const float w1a = W1[ka],      w1b = W1[kb];
        const float w1c = W1[32 + ka], w1d = W1[32 + kb];
        zwlo[2*j2] = TWO_LOG2E * w1a; zwlo[2*j2+1] = TWO_LOG2E * w1b;
        zwhi[2*j2] = TWO_LOG2E * w1c; zwhi[2*j2+1] = TWO_LOG2E * w1d;
        zblo[2*j2] = TWO_LOG2E * b1[ka];      zblo[2*j2+1] = TWO_LOG2E * b1[kb];
        zbhi[2*j2] = TWO_LOG2E * b1[32 + ka]; zbhi[2*j2+1] = TWO_LOG2E * b1[32 + kb];
        const float wa = W2[ka * TWON_ + mn],        wb = W2[kb * TWON_ + mn];
        const float wc = W2[(32 + ka) * TWON_ + mn], wd = W2[(32 + kb) * TWON_ + mn];
        Blo.h2[j2] = __builtin_amdgcn_cvt_pkrtz(wa, wb);
        Bhi.h2[j2] = __builtin_amdgcn_cvt_pkrtz(wc, wd);
        Plo.h2[j2] = __builtin_amdgcn_cvt_pkrtz(w1a * wa, w1b * wb);
        Phi.h2[j2] = __builtin_amdgcn_cvt_pkrtz(w1c * wc, w1d * wd);
    }
    const float b2n = b2[mn];

    // t for this wave's 64 points
    const float treg = t_in[b * T_ + tq];

    // ---- 4 tiles of 16 points each ----
    #pragma unroll
    for (int ti = 0; ti < 4; ++ti) {
        const float tt = __shfl(treg, ti * 16 + mn, 64);

        HPack Ah_lo, Ag_lo, Ah_hi, Ag_hi;
        #pragma unroll
        for (int j2 = 0; j2 < 4; ++j2) {
            // low half (k = k0+2j2, k0+2j2+1)
            float e0 = __builtin_amdgcn_exp2f(fmaf(tt, zwlo[2*j2],   zblo[2*j2]));
            float e1 = __builtin_amdgcn_exp2f(fmaf(tt, zwlo[2*j2+1], zblo[2*j2+1]));
            float r0 = __builtin_amdgcn_rcpf(e0 + 1.0f);
            float r1 = __builtin_amdgcn_rcpf(e1 + 1.0f);
            float h0 = fmaf(-2.0f, r0, 1.0f), h1 = fmaf(-2.0f, r1, 1.0f);
            float g0 = fmaf(-h0, h0, 1.0f),   g1 = fmaf(-h1, h1, 1.0f);
            Ah_lo.h2[j2] = __builtin_amdgcn_cvt_pkrtz(h0, h1);
            Ag_lo.h2[j2] = __builtin_amdgcn_cvt_pkrtz(g0, g1);
            // high half (k+32)
            e0 = __builtin_amdgcn_exp2f(fmaf(tt, zwhi[2*j2],   zbhi[2*j2]));
            e1 = __builtin_amdgcn_exp2f(fmaf(tt, zwhi[2*j2+1], zbhi[2*j2+1]));
            r0 = __builtin_amdgcn_rcpf(e0 + 1.0f);
            r1 = __builtin_amdgcn_rcpf(e1 + 1.0f);
            h0 = fmaf(-2.0f, r0, 1.0f); h1 = fmaf(-2.0f, r1, 1.0f);
            g0 = fmaf(-h0, h0, 1.0f);   g1 = fmaf(-h1, h1, 1.0f);
            Ah_hi.h2[j2] = __builtin_amdgcn_cvt_pkrtz(h0, h1);
            Ag_hi.h2[j2] = __builtin_amdgcn_cvt_pkrtz(g0, g1);
        }

        f32x4 lat = {b2n, b2n, b2n, b2n};
        lat = __builtin_amdgcn_mfma_f32_16x16x32_f16(Ah_lo.h8, Blo.h8, lat, 0, 0, 0);
        lat = __builtin_amdgcn_mfma_f32_16x16x32_f16(Ah_hi.h8, Bhi.h8, lat, 0, 0, 0);
        f32x4 dl = {0.0f, 0.0f, 0.0f, 0.0f};
        dl = __builtin_amdgcn_mfma_f32_16x16x32_f16(Ag_lo.h8, Plo.h8, dl, 0, 0, 0);
        dl = __builtin_amdgcn_mfma_f32_16x16x32_f16(Ag_hi.h8, Phi.h8, dl, 0, 0, 0);

        // C/D: col = lane&15 (=n), row = quad*4 + reg (= point-in-tile)
        const int rowbase = ti * 16 + 4 * q;
        #pragma unroll
        for (int r = 0; r < 4; ++r) {
            spk[(rowbase + r) * PSTRIDE + mn] = __builtin_amdgcn_cvt_pkrtz(lat[r], dl[r]);
        }
    }
    __syncthreads();   // single-wave block: compiles to a waitcnt, no inter-wave coupling

    // ---- epilogue: one thread per point ----
    float lat[TWON_], dlat[TWON_];
    {
        RPack rp;
        const uint4* pr = (const uint4*)&spk[lane * PSTRIDE];  // 80-B rows: 16B aligned
        #pragma unroll
        for (int c = 0; c < 4; ++c) rp.u4[c] = pr[c];
        #pragma unroll
        for (int i = 0; i < TWON_; ++i) { lat[i] = (float)rp.h2[i].x; dlat[i] = (float)rp.h2[i].y; }
    }

    float a[N_], xs[N_], da_[N_], dxs[N_];
    #pragma unroll
    for (int i = 0; i < N_; ++i) { a[i] = lat[i]; da_[i] = dlat[i]; }
    #pragma unroll
    for (int i = 0; i < N_; ++i) {
        const float qm = lat[N_ + i] - pp[N_ + i];   // mu: scalar load
        xs[i]  = qm > 0.0f ? qm : 0.0f;
        dxs[i] = qm > 0.0f ? dlat[N_ + i] : 0.0f;
    }

    float acc = 0.0f;
    #pragma unroll
    for (int k = 0; k < N_; ++k) { const float d = a[k]  - xtv[k];      acc = fmaf(d, d, acc); }
    #pragma unroll
    for (int k = 0; k < N_; ++k) { const float d = xs[k] - xtv[N_ + k]; acc = fmaf(d, d, acc); }

    // physics: rhs_a = g + Pi@x - a ; rhs_x = (Gamma@a)*(mu - x). Pi/Gamma scalar loads.
    const float* Pi  = pp + 2 * N_;
    const float* Gam = pp + 2 * N_ + N_ * N_;
    #pragma unroll
    for (int i = 0; i < N_; ++i) {
        float s1 = pp[i] - a[i];   // g[i]
        #pragma unroll
        for (int j = 0; j < N_; ++j) s1 = fmaf(Pi[i * N_ + j], xs[j], s1);
        float d = da_[i] - s1;
        acc = fmaf(d, d, acc);

        float s2 = 0.0f;
        #pragma unroll
        for (int j = 0; j < N_; ++j) s2 = fmaf(Gam[i * N_ + j], a[j], s2);
        s2 *= (pp[N_ + i] - xs[i]);
        d = dxs[i] - s2;
        acc = fmaf(d, d, acc);
    }

    // scale + wave reduce -> one partial per block (no atomics)
    float v = fmaf(acc, INV_MAIN, sup * INV_SUP);
    float w = wave_reduce(v);
    if (lane == 0) partials[blockIdx.y * gridDim.x + blockIdx.x] = w;
}

// one block of 1024: reduce NPART pre-scaled partials -> scalar
__global__ __launch_bounds__(FBLK)
void pinn_finalize_kernel(const float* __restrict__ partials,
                          float* __restrict__ out) {
    __shared__ float swsum[FBLK / 64];
    const int tid = threadIdx.x;

    const float4* p4 = (const float4*)partials;   // NPART/4 = 4096 float4s
    float v = 0.0f;
    #pragma unroll
    for (int c = 0; c < 4; ++c) {
        const float4 v4 = p4[tid + c * FBLK];
        v += (v4.x + v4.y) + (v4.z + v4.w);
    }

    float w = wave_reduce(v);
    if ((tid & 63) == 0) swsum[tid >> 6] = w;
    __syncthreads();
    if (tid == 0) {
        float s = 0.0f;
        #pragma unroll
        for (int i = 0; i < FBLK / 64; ++i) s += swsum[i];
        out[0] = s;
    }
}

extern "C" void kernel_launch(void* const* d_in, const int* in_sizes, int n_in,
                              void* d_out, int out_size, void* d_ws, size_t ws_size,
                              hipStream_t stream) {
    const float* t_in          = (const float*)d_in[0];
    const float* x_target      = (const float*)d_in[1];
    const float* params_pred   = (const float*)d_in[2];
    const float* params_target = (const float*)d_in[3];
    const float* ic_pred       = (const float*)d_in[4];
    const float* ic_target     = (const float*)d_in[5];
    const float* W1            = (const float*)d_in[6];
    const float* b1            = (const float*)d_in[7];
    const float* W2            = (const float*)d_in[8];
    const float* b2            = (const float*)d_in[9];
    float* out = (float*)d_out;
    float* partials = (float*)d_ws;   // NPART floats = 64 KB

    dim3 grid(NBLKX, B_);
    pinn_main_kernel<<<grid, WBLK, 0, stream>>>(t_in, x_target, params_pred,
                                                params_target, ic_pred, ic_target,
                                                W1, b1, W2, b2, partials);
    pinn_finalize_kernel<<<1, FBLK, 0, stream>>>(partials, out);
}

// Round 7
// 128.242 us; speedup vs baseline: 1.6397x; 1.0198x over previous
//
#include <hip/hip_runtime.h>
#include <math.h>

// Problem constants (match reference)
#define B_    256
#define T_    4096
#define N_    8        // n
#define TWON_ 16       // 2n
#define H_    64
#define P_    144      // 2n + 2n^2
#define WBLK  64                 // one wave per block
#define NBLKX (T_ / WBLK)        // 64 blocks along T
#define NPART (NBLKX * B_)       // 16384 partials
#define PSTRIDE 20               // LDS row stride in half2 units: 80 B rows, 16B-aligned
#define FBLK  1024               // finalize block size

// denominators
#define INV_MAIN  (1.0f / (float)(B_ * TWON_ * T_))   // 1/16777216
#define INV_SUP   (1.0f / (float)(B_ * (P_ + TWON_))) // 1/40960

#define TWO_LOG2E 2.8853900817779268f   // 2*log2(e): e^{2x} = 2^{x*TWO_LOG2E}

typedef __fp16   half2_t __attribute__((ext_vector_type(2)));  // cvt_pkrtz result type
typedef _Float16 half8_t __attribute__((ext_vector_type(8)));  // MFMA operand type
typedef float    f32x4   __attribute__((ext_vector_type(4)));

union HPack { half2_t h2[4]; half8_t h8; };   // MFMA operand pun
union RPack { uint4 u4[4]; half2_t h2[16]; }; // LDS row read pun (64 B)

__device__ __forceinline__ float wave_reduce(float v) {
    #pragma unroll
    for (int off = 32; off > 0; off >>= 1) v += __shfl_down(v, off, 64);
    return v;
}

// grid: (NBLKX, B_), block = 64 (one wave). Wave computes its 64 points via
// 4 MFMA tiles of 16 points; lat/dlat round-trip LDS packed half2 (5.1 KB).
// x_target loads issued AFTER the MFMA phase (keeps MLP-phase VGPR peak low;
// latency still hidden behind LDS round-trip). launch_bounds(64,6): 6 waves/EU.
__global__ __launch_bounds__(WBLK, 6)
void pinn_main_kernel(const float* __restrict__ t_in,
                      const float* __restrict__ x_target,
                      const float* __restrict__ params_pred,
                      const float* __restrict__ params_target,
                      const float* __restrict__ ic_pred,
                      const float* __restrict__ ic_target,
                      const float* __restrict__ W1,
                      const float* __restrict__ b1,
                      const float* __restrict__ W2,
                      const float* __restrict__ b2,
                      float* __restrict__ partials) {
    __shared__ __align__(16) half2_t spk[WBLK * PSTRIDE];  // 5.1 KB: (lat, dlat) packed

    const int lane = threadIdx.x;    // 0..63
    const int b    = blockIdx.y;
    const int q    = lane >> 4;      // quad
    const int mn   = lane & 15;      // A-row (point-in-tile) == B/C col n
    const int k0   = q * 8;          // this lane's k-group base (within K=32 half)

    const float* pp = params_pred + b * P_;   // uniform -> scalar loads
    const int tq = blockIdx.x * WBLK + lane;

    // ---- supervised loss (blocks with x==0; one per batch) ----
    float sup = 0.0f;
    if (blockIdx.x == 0) {
        #pragma unroll
        for (int i = lane; i < P_; i += WBLK) {   // 144 elems
            const float d = pp[i] - params_target[b * P_ + i];
            sup = fmaf(d, d, sup);
        }
        if (lane < TWON_) {
            const float d = ic_pred[b * TWON_ + lane] - ic_target[b * TWON_ + lane];
            sup = fmaf(d, d, sup);
        }
    }

    // ---- per-lane weight setup ----
    // E = e^{2x} = exp2(x*2log2e); tanh = 1 - 2/(E+1). exp2 limits give h=+-1, g=0.
    float zwlo[8], zblo[8], zwhi[8], zbhi[8];
    HPack Blo, Bhi, Plo, Phi;   // B[k][n]=W2[k][n]; B'[k][n]=W1[k]*W2[k][n]
    #pragma unroll
    for (int j2 = 0; j2 < 4; ++j2) {
        const int ka = k0 + 2 * j2, kb = ka + 1;
        const float w1a = W1[ka],      w1b = W1[kb];
        const float w1c = W1[32 + ka], w1d = W1[32 + kb];
        zwlo[2*j2] = TWO_LOG2E * w1a; zwlo[2*j2+1] = TWO_LOG2E * w1b;
        zwhi[2*j2] = TWO_LOG2E * w1c; zwhi[2*j2+1] = TWO_LOG2E * w1d;
        zblo[2*j2] = TWO_LOG2E * b1[ka];      zblo[2*j2+1] = TWO_LOG2E * b1[kb];
        zbhi[2*j2] = TWO_LOG2E * b1[32 + ka]; zbhi[2*j2+1] = TWO_LOG2E * b1[32 + kb];
        const float wa = W2[ka * TWON_ + mn],        wb = W2[kb * TWON_ + mn];
        const float wc = W2[(32 + ka) * TWON_ + mn], wd = W2[(32 + kb) * TWON_ + mn];
        Blo.h2[j2] = __builtin_amdgcn_cvt_pkrtz(wa, wb);
        Bhi.h2[j2] = __builtin_amdgcn_cvt_pkrtz(wc, wd);
        Plo.h2[j2] = __builtin_amdgcn_cvt_pkrtz(w1a * wa, w1b * wb);
        Phi.h2[j2] = __builtin_amdgcn_cvt_pkrtz(w1c * wc, w1d * wd);
    }
    const float b2n = b2[mn];

    // t for this wave's 64 points
    const float treg = t_in[b * T_ + tq];

    // ---- 4 tiles of 16 points each ----
    #pragma unroll
    for (int ti = 0; ti < 4; ++ti) {
        const float tt = __shfl(treg, ti * 16 + mn, 64);

        HPack Ah_lo, Ag_lo, Ah_hi, Ag_hi;
        #pragma unroll
        for (int j2 = 0; j2 < 4; ++j2) {
            // low half (k = k0+2j2, k0+2j2+1)
            float e0 = __builtin_amdgcn_exp2f(fmaf(tt, zwlo[2*j2],   zblo[2*j2]));
            float e1 = __builtin_amdgcn_exp2f(fmaf(tt, zwlo[2*j2+1], zblo[2*j2+1]));
            float r0 = __builtin_amdgcn_rcpf(e0 + 1.0f);
            float r1 = __builtin_amdgcn_rcpf(e1 + 1.0f);
            float h0 = fmaf(-2.0f, r0, 1.0f), h1 = fmaf(-2.0f, r1, 1.0f);
            float g0 = fmaf(-h0, h0, 1.0f),   g1 = fmaf(-h1, h1, 1.0f);
            Ah_lo.h2[j2] = __builtin_amdgcn_cvt_pkrtz(h0, h1);
            Ag_lo.h2[j2] = __builtin_amdgcn_cvt_pkrtz(g0, g1);
            // high half (k+32)
            e0 = __builtin_amdgcn_exp2f(fmaf(tt, zwhi[2*j2],   zbhi[2*j2]));
            e1 = __builtin_amdgcn_exp2f(fmaf(tt, zwhi[2*j2+1], zbhi[2*j2+1]));
            r0 = __builtin_amdgcn_rcpf(e0 + 1.0f);
            r1 = __builtin_amdgcn_rcpf(e1 + 1.0f);
            h0 = fmaf(-2.0f, r0, 1.0f); h1 = fmaf(-2.0f, r1, 1.0f);
            g0 = fmaf(-h0, h0, 1.0f);   g1 = fmaf(-h1, h1, 1.0f);
            Ah_hi.h2[j2] = __builtin_amdgcn_cvt_pkrtz(h0, h1);
            Ag_hi.h2[j2] = __builtin_amdgcn_cvt_pkrtz(g0, g1);
        }

        f32x4 lat = {b2n, b2n, b2n, b2n};
        lat = __builtin_amdgcn_mfma_f32_16x16x32_f16(Ah_lo.h8, Blo.h8, lat, 0, 0, 0);
        lat = __builtin_amdgcn_mfma_f32_16x16x32_f16(Ah_hi.h8, Bhi.h8, lat, 0, 0, 0);
        f32x4 dl = {0.0f, 0.0f, 0.0f, 0.0f};
        dl = __builtin_amdgcn_mfma_f32_16x16x32_f16(Ag_lo.h8, Plo.h8, dl, 0, 0, 0);
        dl = __builtin_amdgcn_mfma_f32_16x16x32_f16(Ag_hi.h8, Phi.h8, dl, 0, 0, 0);

        // C/D: col = lane&15 (=n), row = quad*4 + reg (= point-in-tile)
        const int rowbase = ti * 16 + 4 * q;
        #pragma unroll
        for (int r = 0; r < 4; ++r) {
            spk[(rowbase + r) * PSTRIDE + mn] = __builtin_amdgcn_cvt_pkrtz(lat[r], dl[r]);
        }
    }

    // ---- x_target loads: issued NOW (post-MFMA) so their 16 VGPRs are not
    // live across the MLP phase; latency hidden by LDS round-trip below ----
    const float* xt = x_target + (size_t)b * TWON_ * T_ + tq;
    float xtv[TWON_];
    #pragma unroll
    for (int k = 0; k < TWON_; ++k) xtv[k] = xt[(size_t)k * T_];

    __syncthreads();   // single-wave block: lgkmcnt wait + trivial barrier

    // ---- epilogue: one thread per point ----
    float lat[TWON_], dlat[TWON_];
    {
        RPack rp;
        const uint4* pr = (const uint4*)&spk[lane * PSTRIDE];  // 80-B rows: 16B aligned
        #pragma unroll
        for (int c = 0; c < 4; ++c) rp.u4[c] = pr[c];
        #pragma unroll
        for (int i = 0; i < TWON_; ++i) { lat[i] = (float)rp.h2[i].x; dlat[i] = (float)rp.h2[i].y; }
    }

    float a[N_], xs[N_], da_[N_], dxs[N_];
    #pragma unroll
    for (int i = 0; i < N_; ++i) { a[i] = lat[i]; da_[i] = dlat[i]; }
    #pragma unroll
    for (int i = 0; i < N_; ++i) {
        const float qm = lat[N_ + i] - pp[N_ + i];   // mu: scalar load
        xs[i]  = qm > 0.0f ? qm : 0.0f;
        dxs[i] = qm > 0.0f ? dlat[N_ + i] : 0.0f;
    }

    float acc = 0.0f;
    #pragma unroll
    for (int k = 0; k < N_; ++k) { const float d = a[k]  - xtv[k];      acc = fmaf(d, d, acc); }
    #pragma unroll
    for (int k = 0; k < N_; ++k) { const float d = xs[k] - xtv[N_ + k]; acc = fmaf(d, d, acc); }

    // physics: rhs_a = g + Pi@x - a ; rhs_x = (Gamma@a)*(mu - x). Pi/Gamma scalar loads.
    const float* Pi  = pp + 2 * N_;
    const float* Gam = pp + 2 * N_ + N_ * N_;
    #pragma unroll
    for (int i = 0; i < N_; ++i) {
        float s1 = pp[i] - a[i];   // g[i]
        #pragma unroll
        for (int j = 0; j < N_; ++j) s1 = fmaf(Pi[i * N_ + j], xs[j], s1);
        float d = da_[i] - s1;
        acc = fmaf(d, d, acc);

        float s2 = 0.0f;
        #pragma unroll
        for (int j = 0; j < N_; ++j) s2 = fmaf(Gam[i * N_ + j], a[j], s2);
        s2 *= (pp[N_ + i] - xs[i]);
        d = dxs[i] - s2;
        acc = fmaf(d, d, acc);
    }

    // scale + wave reduce -> one partial per block (no atomics)
    float v = fmaf(acc, INV_MAIN, sup * INV_SUP);
    float w = wave_reduce(v);
    if (lane == 0) partials[blockIdx.y * gridDim.x + blockIdx.x] = w;
}

// one block of 1024: reduce NPART pre-scaled partials -> scalar
__global__ __launch_bounds__(FBLK)
void pinn_finalize_kernel(const float* __restrict__ partials,
                          float* __restrict__ out) {
    __shared__ float swsum[FBLK / 64];
    const int tid = threadIdx.x;

    const float4* p4 = (const float4*)partials;   // NPART/4 = 4096 float4s
    float v = 0.0f;
    #pragma unroll
    for (int c = 0; c < 4; ++c) {
        const float4 v4 = p4[tid + c * FBLK];
        v += (v4.x + v4.y) + (v4.z + v4.w);
    }

    float w = wave_reduce(v);
    if ((tid & 63) == 0) swsum[tid >> 6] = w;
    __syncthreads();
    if (tid == 0) {
        float s = 0.0f;
        #pragma unroll
        for (int i = 0; i < FBLK / 64; ++i) s += swsum[i];
        out[0] = s;
    }
}

extern "C" void kernel_launch(void* const* d_in, const int* in_sizes, int n_in,
                              void* d_out, int out_size, void* d_ws, size_t ws_size,
                              hipStream_t stream) {
    const float* t_in          = (const float*)d_in[0];
    const float* x_target      = (const float*)d_in[1];
    const float* params_pred   = (const float*)d_in[2];
    const float* params_target = (const float*)d_in[3];
    const float* ic_pred       = (const float*)d_in[4];
    const float* ic_target     = (const float*)d_in[5];
    const float* W1            = (const float*)d_in[6];
    const float* b1            = (const float*)d_in[7];
    const float* W2            = (const float*)d_in[8];
    const float* b2            = (const float*)d_in[9];
    float* out = (float*)d_out;
    float* partials = (float*)d_ws;   // NPART floats = 64 KB

    dim3 grid(NBLKX, B_);
    pinn_main_kernel<<<grid, WBLK, 0, stream>>>(t_in, x_target, params_pred,
                                                params_target, ic_pred, ic_target,
                                                W1, b1, W2, b2, partials);
    pinn_finalize_kernel<<<1, FBLK, 0, stream>>>(partials, out);
}